// Round 2
// baseline (1474.310 us; speedup 1.0000x reference)
//
#include <hip/hip_runtime.h>
#include <math.h>

#define D 32
#define CD 16
#define HID 64
#define DIN 48
#define TPAD 36            // padded row stride: 144B, 16B-aligned, bank stride 4
#define IPB 8              // items per 256-thread block (1 item per 32 lanes)

// Compiler-only memory fence: DS ops from one wave are processed in order by
// the LDS pipe; this stops the compiler from reordering LDS accesses across
// cross-lane write->read points. All LDS traffic here is wave-local.
#define MEMFENCE() __asm__ volatile("" ::: "memory")

static __device__ __forceinline__ float fast_rcp(float x) {
#if __has_builtin(__builtin_amdgcn_rcpf)
    return __builtin_amdgcn_rcpf(x);
#else
    return 1.0f / x;
#endif
}

__global__ __launch_bounds__(256, 3) void kalman_step_kernel(
    const float* __restrict__ x_post,
    const float* __restrict__ P_post,
    const float* __restrict__ ctx,
    const float* __restrict__ meas,
    const float* __restrict__ W1,
    const float* __restrict__ b1,
    const float* __restrict__ W2,
    const float* __restrict__ b2,
    const float* __restrict__ Hm,
    const float* __restrict__ logQ,
    const float* __restrict__ logR,
    float* __restrict__ out,
    int B)
{
    __shared__ float Tbuf[IPB][D * TPAD];      // HP rows -> later W rows (+v at col 32)
    __shared__ float Sbuf[IPB][DIN + HID + D]; // xc | h | x_pred
    __shared__ float Pbuf[IPB][68];            // GJ pivot-row broadcast: s|w|y

    const int t = threadIdx.x;
    const int slot = t >> 5;     // item slot within block
    const int c = t & 31;        // lane-within-item: column index (row index for S/GJ)
    const int item = blockIdx.x * IPB + slot;
    if (item >= B) return;

    float* Ts   = Tbuf[slot];
    float* xcb  = Sbuf[slot];
    float* hbuf = xcb + DIN;
    float* xpb  = hbuf + HID;
    float* Pb   = Pbuf[slot];

    // ---------------- MLP predict: h = tanh(W1 [x;ctx] + b1); x_pred = W2 h + b2
    xcb[c] = x_post[(size_t)item * D + c];
    if (c < CD) xcb[D + c] = ctx[(size_t)item * CD + c];
    MEMFENCE();

    float xr[DIN];
    #pragma unroll
    for (int j = 0; j < DIN; ++j) xr[j] = xcb[j];   // broadcast reads

    float a0 = b1[c], a1 = b1[c + 32];
    #pragma unroll
    for (int j = 0; j < DIN; ++j) {
        a0 = fmaf(W1[c * DIN + j], xr[j], a0);
        a1 = fmaf(W1[(c + 32) * DIN + j], xr[j], a1);
    }
    hbuf[c]      = tanhf(a0);
    hbuf[c + 32] = tanhf(a1);
    MEMFENCE();

    float xpv = b2[c];
    #pragma unroll
    for (int j = 0; j < HID; ++j) xpv = fmaf(W2[c * HID + j], hbuf[j], xpv);
    xpb[c] = xpv;
    MEMFENCE();

    // ---------------- P_pred column c (== row c, symmetric) in registers
    float p[D];
    #pragma unroll
    for (int i = 0; i < D; ++i)
        p[i] = P_post[(size_t)item * D * D + (size_t)i * D + c];
    float qc = __expf(logQ[c]);
    #pragma unroll
    for (int i = 0; i < D; ++i) p[i] += (i == c) ? qc : 0.0f;

    // ---------------- innovation y[c] = meas[c] - (H x_pred)[c]
    float yv = meas[(size_t)item * D + c];
    #pragma unroll
    for (int j = 0; j < D; ++j) yv = fmaf(-Hm[c * D + j], xpb[j], yv);

    // ---------------- HP column c: hp[i] = sum_j H[i,j] P[j,c]
    float hp[D];
    #pragma unroll
    for (int i = 0; i < D; ++i) {
        float acc = 0.0f;
        #pragma unroll
        for (int j = 0; j < D; ++j) acc = fmaf(Hm[i * D + j], p[j], acc);
        hp[i] = acc;
    }

    // ---------------- transpose HP through LDS: w[] = HP row c (GJ RHS rows)
    #pragma unroll
    for (int i = 0; i < D; ++i) Ts[i * TPAD + c] = hp[i];
    MEMFENCE();
    float w[D];
    #pragma unroll
    for (int j = 0; j < D; ++j) w[j] = Ts[c * TPAD + j];
    MEMFENCE();

    // ---------------- S row c: s[i] = sum_j HP[c,j] H[i,j] + (R+1e-6) diag
    float s[D];
    float rc = __expf(logR[c]) + 1e-6f;
    #pragma unroll
    for (int i = 0; i < D; ++i) {
        float acc = 0.0f;
        #pragma unroll
        for (int j = 0; j < D; ++j) acc = fmaf(Hm[i * D + j], w[j], acc);
        s[i] = acc + ((i == c) ? rc : 0.0f);
    }

    // ---------------- Gauss-Jordan with partial pivoting on [S | HP_row | y]
    // Lane c = row c. Pivot rows left unscaled; one deferred scale at the end.
    bool act = true;
    float dr = 1.0f;
    int pr = 0;
    #pragma unroll
    for (int k = 0; k < D; ++k) {
        // pivot selection: argmax |s[k]| among active rows (min index on tie)
        float key = act ? fabsf(s[k]) : -1.0f;
        int best = c;
        #pragma unroll
        for (int off = 16; off > 0; off >>= 1) {
            float ok = __shfl_xor(key, off, 32);
            int   ob = __shfl_xor(best, off, 32);
            bool take = (ok > key) || (ok == key && ob < best);
            key  = take ? ok : key;
            best = take ? ob : best;
        }
        bool ispiv = (c == best);
        if (ispiv) {
            #pragma unroll
            for (int j = 0; j < D; ++j) if (j >= k) Pb[j] = s[j];
            #pragma unroll
            for (int j = 0; j < D; ++j) Pb[D + j] = w[j];
            Pb[2 * D] = yv;
        }
        MEMFENCE();
        float pk = Pb[k];
        float pinv = fast_rcp(pk);
        float tt = ispiv ? 0.0f : s[k] * pinv;   // Jordan: all non-pivot rows eliminate
        dr = ispiv ? pk : dr;
        pr = ispiv ? k : pr;
        act = act && !ispiv;
        #pragma unroll
        for (int j = 0; j < D; ++j) if (j > k) s[j] = fmaf(-tt, Pb[j], s[j]);
        #pragma unroll
        for (int j = 0; j < D; ++j) w[j] = fmaf(-tt, Pb[D + j], w[j]);
        yv = fmaf(-tt, Pb[2 * D], yv);
        MEMFENCE();   // all lanes done reading Pb before next step's publish
    }

    // deferred scaling: lane pivoted at step pr holds W row pr (= d_r * row)
    float inv = fast_rcp(dr);
    #pragma unroll
    for (int j = 0; j < D; ++j) w[j] *= inv;
    float vv = yv * inv;

    // publish W rows (+ v) into Ts (HP rows there are dead; hp[] is in regs)
    #pragma unroll
    for (int j = 0; j < D; ++j) Ts[pr * TPAD + j] = w[j];
    Ts[pr * TPAD + D] = vv;
    MEMFENCE();

    // ---------------- x_upd[c] = x_pred[c] + sum_j HP[j,c] v[j]
    // ---------------- P_upd[i,c] = P[i,c] - sum_j HP[j,c] W[j,i]
    float acc[D];
    #pragma unroll
    for (int i = 0; i < D; ++i) acc[i] = 0.0f;
    float xu = xpv;
    #pragma unroll
    for (int j = 0; j < D; ++j) {
        float hj = hp[j];
        xu = fmaf(hj, Ts[j * TPAD + D], xu);
        #pragma unroll
        for (int i = 0; i < D; ++i)
            acc[i] = fmaf(hj, Ts[j * TPAD + i], acc[i]);  // broadcast reads
    }

    float* out_x = out;
    float* out_P = out + (size_t)B * D;
    out_x[(size_t)item * D + c] = xu;
    #pragma unroll
    for (int i = 0; i < D; ++i)
        out_P[(size_t)item * D * D + (size_t)i * D + c] = p[i] - acc[i];
}

extern "C" void kernel_launch(void* const* d_in, const int* in_sizes, int n_in,
                              void* d_out, int out_size, void* d_ws, size_t ws_size,
                              hipStream_t stream) {
    const float* x_post = (const float*)d_in[0];
    const float* P_post = (const float*)d_in[1];
    const float* ctx    = (const float*)d_in[2];
    const float* meas   = (const float*)d_in[3];
    const float* W1     = (const float*)d_in[4];
    const float* b1     = (const float*)d_in[5];
    const float* W2     = (const float*)d_in[6];
    const float* b2     = (const float*)d_in[7];
    const float* Hm     = (const float*)d_in[8];
    const float* logQ   = (const float*)d_in[9];
    const float* logR   = (const float*)d_in[10];
    (void)n_in; (void)d_ws; (void)ws_size; (void)out_size;

    int B = in_sizes[0] / D;
    int blocks = (B + IPB - 1) / IPB;
    kalman_step_kernel<<<blocks, 256, 0, stream>>>(
        x_post, P_post, ctx, meas, W1, b1, W2, b2, Hm, logQ, logR,
        (float*)d_out, B);
}